// Round 1
// baseline (566.869 us; speedup 1.0000x reference)
//
#include <hip/hip_runtime.h>
#include <hip/hip_bf16.h>
#include <stdint.h>

#define NTOK 32768
#define HD 1024
#define FD 512
#define NEXP 8
#define TAU 5e-4f

typedef __attribute__((ext_vector_type(8))) short short8;
typedef __attribute__((ext_vector_type(4))) float f32x4;

__device__ __forceinline__ short f2bh(float f) {
  uint32_t u = __float_as_uint(f);
  return (short)((u + 0x7fffu + ((u >> 16) & 1u)) >> 16);
}
__device__ __forceinline__ float bh2f(short h) {
  return __uint_as_float(((uint32_t)(uint16_t)h) << 16);
}

// ---------------------------------------------------------------------------
// Transpose + bf16 split: src [rows][cols] f32 -> dstH/dstL [cols][rows] bf16
// ---------------------------------------------------------------------------
__global__ __launch_bounds__(256) void k_transpose_split(
    const float* __restrict__ src, short* __restrict__ dstH,
    short* __restrict__ dstL, int rows, int cols) {
  __shared__ float tile[32][33];
  size_t msz = (size_t)rows * cols;
  src  += (size_t)blockIdx.z * msz;
  dstH += (size_t)blockIdx.z * msz;
  if (dstL) dstL += (size_t)blockIdx.z * msz;
  int c0 = blockIdx.x * 32, r0 = blockIdx.y * 32;
  int tx = threadIdx.x & 31, ty = threadIdx.x >> 5;
#pragma unroll
  for (int i = 0; i < 32; i += 8)
    tile[ty + i][tx] = src[(size_t)(r0 + ty + i) * cols + c0 + tx];
  __syncthreads();
#pragma unroll
  for (int i = 0; i < 32; i += 8) {
    float v = tile[tx][ty + i];
    short h = f2bh(v);
    size_t di = (size_t)(c0 + ty + i) * rows + r0 + tx;
    dstH[di] = h;
    if (dstL) dstL[di] = f2bh(v - bh2f(h));
  }
}

// ---------------------------------------------------------------------------
// GEMM1: h = relu(x@W1 + b1) via bf16x3 emulated fp32, fused partial logits.
// Tile 128(M tokens) x 128(N f) x K32, 4 waves, each wave 64x64.
// part[t][ntile(4)][e(8)] fp32.
// ---------------------------------------------------------------------------
__global__ __launch_bounds__(256) void k_gemm1(
    const float* __restrict__ x, const short* __restrict__ W1hT,
    const short* __restrict__ W1lT, const float* __restrict__ b1,
    const float* __restrict__ W2, float* __restrict__ part) {
  __shared__ __align__(16) char smem[40960];
  short (*Ah)[40] = (short (*)[40])(smem);
  short (*Al)[40] = (short (*)[40])(smem + 10240);
  short (*Bh)[40] = (short (*)[40])(smem + 20480);
  short (*Bl)[40] = (short (*)[40])(smem + 30720);

  const int tid = threadIdx.x;
  const int lane = tid & 63, wave = tid >> 6;
  const int wr = wave >> 1, wc = wave & 1;
  const int fr = lane & 15, fg = lane >> 4;
  const int m0 = blockIdx.x * 128, n0 = blockIdx.y * 128;
  const int by = blockIdx.y;

  const int r = tid >> 1, seg = tid & 1, s16 = seg * 16;
  const float* xa = x + (size_t)(m0 + r) * HD + s16;
  const short* wh = W1hT + (size_t)(n0 + r) * HD + s16;
  const short* wl = W1lT + (size_t)(n0 + r) * HD + s16;

  f32x4 acc[4][4];
#pragma unroll
  for (int i = 0; i < 4; ++i)
#pragma unroll
    for (int j = 0; j < 4; ++j) acc[i][j] = (f32x4){0.f, 0.f, 0.f, 0.f};

  for (int k0 = 0; k0 < HD; k0 += 32) {
    f32x4 v0 = *(const f32x4*)(xa + k0);
    f32x4 v1 = *(const f32x4*)(xa + k0 + 4);
    f32x4 v2 = *(const f32x4*)(xa + k0 + 8);
    f32x4 v3 = *(const f32x4*)(xa + k0 + 12);
    short8 ph0, ph1, pl0, pl1;
#pragma unroll
    for (int q = 0; q < 4; ++q) {
      { float f = v0[q]; short h = f2bh(f); ph0[q]     = h; pl0[q]     = f2bh(f - bh2f(h)); }
      { float f = v1[q]; short h = f2bh(f); ph0[4 + q] = h; pl0[4 + q] = f2bh(f - bh2f(h)); }
      { float f = v2[q]; short h = f2bh(f); ph1[q]     = h; pl1[q]     = f2bh(f - bh2f(h)); }
      { float f = v3[q]; short h = f2bh(f); ph1[4 + q] = h; pl1[4 + q] = f2bh(f - bh2f(h)); }
    }
    short8 bh0 = *(const short8*)(wh + k0);
    short8 bh1 = *(const short8*)(wh + k0 + 8);
    short8 bl0 = *(const short8*)(wl + k0);
    short8 bl1 = *(const short8*)(wl + k0 + 8);
    *(short8*)&Ah[r][s16]     = ph0;
    *(short8*)&Ah[r][s16 + 8] = ph1;
    *(short8*)&Al[r][s16]     = pl0;
    *(short8*)&Al[r][s16 + 8] = pl1;
    *(short8*)&Bh[r][s16]     = bh0;
    *(short8*)&Bh[r][s16 + 8] = bh1;
    *(short8*)&Bl[r][s16]     = bl0;
    *(short8*)&Bl[r][s16 + 8] = bl1;
    __syncthreads();

    short8 af[4], alf[4], bf[4], blf[4];
#pragma unroll
    for (int i = 0; i < 4; ++i) {
      af[i]  = *(const short8*)&Ah[wr * 64 + i * 16 + fr][fg * 8];
      alf[i] = *(const short8*)&Al[wr * 64 + i * 16 + fr][fg * 8];
      bf[i]  = *(const short8*)&Bh[wc * 64 + i * 16 + fr][fg * 8];
      blf[i] = *(const short8*)&Bl[wc * 64 + i * 16 + fr][fg * 8];
    }
#pragma unroll
    for (int i = 0; i < 4; ++i)
#pragma unroll
      for (int j = 0; j < 4; ++j) {
        acc[i][j] = __builtin_amdgcn_mfma_f32_16x16x32_bf16(af[i],  bf[j],  acc[i][j], 0, 0, 0);
        acc[i][j] = __builtin_amdgcn_mfma_f32_16x16x32_bf16(af[i],  blf[j], acc[i][j], 0, 0, 0);
        acc[i][j] = __builtin_amdgcn_mfma_f32_16x16x32_bf16(alf[i], bf[j],  acc[i][j], 0, 0, 0);
      }
    __syncthreads();
  }

  // Epilogue: relu(acc+b1) -> LDS (64 rows per pass), partial logits -> part
  float* hl64 = (float*)smem;            // [64][129]
  float* W2c  = (float*)(smem + 33024);  // [128][8]
  *(f32x4*)(W2c + tid * 4) = *(const f32x4*)(W2 + (size_t)n0 * NEXP + tid * 4);
  float b1j[4];
#pragma unroll
  for (int j = 0; j < 4; ++j) b1j[j] = b1[n0 + wc * 64 + j * 16 + fr];

  for (int p = 0; p < 2; ++p) {
    if (wr == p) {
#pragma unroll
      for (int i = 0; i < 4; ++i)
#pragma unroll
        for (int j = 0; j < 4; ++j) {
          int col = wc * 64 + j * 16 + fr;
#pragma unroll
          for (int q = 0; q < 4; ++q) {
            int rowl = i * 16 + fg * 4 + q;
            hl64[rowl * 129 + col] = fmaxf(acc[i][j][q] + b1j[j], 0.f);
          }
        }
    }
    __syncthreads();
    if (tid < 128) {
      int r2 = tid & 63, eh = tid >> 6;
      const float* hrow = hl64 + r2 * 129;
      const float* wcp = W2c + eh * 4;
      float s0 = 0.f, s1 = 0.f, s2 = 0.f, s3 = 0.f;
      for (int f = 0; f < 128; ++f) {
        float hv = hrow[f];
        s0 += hv * wcp[f * 8 + 0];
        s1 += hv * wcp[f * 8 + 1];
        s2 += hv * wcp[f * 8 + 2];
        s3 += hv * wcp[f * 8 + 3];
      }
      float* pp = part + (size_t)(m0 + p * 64 + r2) * 32 + by * 8 + eh * 4;
      pp[0] = s0; pp[1] = s1; pp[2] = s2; pp[3] = s3;
    }
    __syncthreads();
  }
}

// ---------------------------------------------------------------------------
// Combine partial logits, argmax (first-max-wins), flag near-ties.
// ---------------------------------------------------------------------------
__global__ __launch_bounds__(256) void k_combine(
    const float* __restrict__ part, const float* __restrict__ b2,
    int* __restrict__ sel, int* __restrict__ flagged, int* __restrict__ nflag) {
  int t = blockIdx.x * 256 + threadIdx.x;
  const float* p = part + (size_t)t * 32;
  float lg[8];
#pragma unroll
  for (int e = 0; e < 8; ++e) lg[e] = p[e] + p[8 + e] + p[16 + e] + p[24 + e] + b2[e];
  int be = 0; float best = lg[0];
#pragma unroll
  for (int e = 1; e < 8; ++e) if (lg[e] > best) { best = lg[e]; be = e; }
  float second = -3.4e38f;
#pragma unroll
  for (int e = 0; e < 8; ++e) if (e != be && lg[e] > second) second = lg[e];
  sel[t] = be;
  if (best - second < TAU) {
    int ix = atomicAdd(nflag, 1);
    if (ix < NTOK) flagged[ix] = t;
  }
}

// ---------------------------------------------------------------------------
// Exact (fp64) routing recompute for flagged near-tie tokens.
// ---------------------------------------------------------------------------
__global__ __launch_bounds__(256) void k_recompute(
    const float* __restrict__ x, const float* __restrict__ W1,
    const float* __restrict__ b1, const float* __restrict__ W2,
    const float* __restrict__ b2, const int* __restrict__ flagged,
    const int* __restrict__ nflag, int* __restrict__ sel) {
  __shared__ float xs[1024];
  __shared__ double hs[512];
  __shared__ double lgs[8];
  int nf = *nflag; if (nf > NTOK) nf = NTOK;
  for (int fi = blockIdx.x; fi < nf; fi += gridDim.x) {
    int t = flagged[fi];
    __syncthreads();
    for (int q = threadIdx.x; q < 1024; q += 256) xs[q] = x[(size_t)t * HD + q];
    __syncthreads();
    int f0 = threadIdx.x * 2;
    double a0 = 0.0, a1 = 0.0;
    for (int h = 0; h < 1024; ++h) {
      double xv = (double)xs[h];
      a0 += xv * (double)W1[h * FD + f0];
      a1 += xv * (double)W1[h * FD + f0 + 1];
    }
    a0 += (double)b1[f0]; a1 += (double)b1[f0 + 1];
    hs[f0]     = a0 > 0.0 ? a0 : 0.0;
    hs[f0 + 1] = a1 > 0.0 ? a1 : 0.0;
    __syncthreads();
    if (threadIdx.x < 8) {
      int e = threadIdx.x;
      double s = 0.0;
      for (int f = 0; f < 512; ++f) s += hs[f] * (double)W2[f * 8 + e];
      lgs[e] = s + (double)b2[e];
    }
    __syncthreads();
    if (threadIdx.x == 0) {
      int be = 0; double best = lgs[0];
      for (int e = 1; e < 8; ++e) if (lgs[e] > best) { best = lgs[e]; be = e; }
      sel[t] = be;
    }
  }
}

// ---------------------------------------------------------------------------
// Compact tokens into per-expert lists.
// ---------------------------------------------------------------------------
__global__ __launch_bounds__(256) void k_compact(
    const int* __restrict__ sel, int* __restrict__ cnt, int* __restrict__ list) {
  int t = blockIdx.x * 256 + threadIdx.x;
  int e = sel[t];
  int p = atomicAdd(&cnt[e], 1);
  list[(size_t)e * NTOK + p] = t;
}

__global__ void k_build_desc(const int* __restrict__ cnt, int* __restrict__ desc,
                             int* __restrict__ ntl) {
  if (threadIdx.x == 0 && blockIdx.x == 0) {
    int n = 0;
    for (int e = 0; e < 8; ++e) {
      int m = (cnt[e] + 127) >> 7;
      for (int i = 0; i < m; ++i) desc[n++] = (e << 16) | i;
    }
    *ntl = n;
  }
}

// ---------------------------------------------------------------------------
// Grouped expert GEMM: out[t] = x[t] @ expert_W[e] + expert_b[e], bf16 MFMA.
// Tile 128(tokens, gathered) x 128(d) x K32.
// ---------------------------------------------------------------------------
__global__ __launch_bounds__(256) void k_gemm2(
    const float* __restrict__ x, const short* __restrict__ WexpT,
    const float* __restrict__ expert_b, const int* __restrict__ cnt,
    const int* __restrict__ list, const int* __restrict__ desc,
    const int* __restrict__ ntl, float* __restrict__ out) {
  if ((int)blockIdx.x >= *ntl) return;
  int dsc = desc[blockIdx.x];
  int e = dsc >> 16, mt = dsc & 0xffff;
  int ce = cnt[e];
  int mb = mt * 128;
  int rows = ce - mb; if (rows > 128) rows = 128;

  __shared__ int toks[128];
  __shared__ short Ah[128][40];
  __shared__ short Bh[128][40];
  const int tid = threadIdx.x;
  if (tid < 128) {
    int idx = mb + tid;
    toks[tid] = list[(size_t)e * NTOK + (idx < ce ? idx : mb)];
  }
  __syncthreads();

  const int lane = tid & 63, wave = tid >> 6;
  const int wr = wave >> 1, wcc = wave & 1;
  const int fr = lane & 15, fg = lane >> 4;
  const int n0 = blockIdx.y * 128;
  const int r = tid >> 1, seg = tid & 1, s16 = seg * 16;
  const float* xa = x + (size_t)toks[r] * HD + s16;
  const short* wb = WexpT + ((size_t)e << 20) + (size_t)(n0 + r) * HD + s16;

  f32x4 acc[4][4];
#pragma unroll
  for (int i = 0; i < 4; ++i)
#pragma unroll
    for (int j = 0; j < 4; ++j) acc[i][j] = (f32x4){0.f, 0.f, 0.f, 0.f};

  for (int k0 = 0; k0 < HD; k0 += 32) {
    f32x4 v0 = *(const f32x4*)(xa + k0);
    f32x4 v1 = *(const f32x4*)(xa + k0 + 4);
    f32x4 v2 = *(const f32x4*)(xa + k0 + 8);
    f32x4 v3 = *(const f32x4*)(xa + k0 + 12);
    short8 ph0, ph1;
#pragma unroll
    for (int q = 0; q < 4; ++q) {
      ph0[q]     = f2bh(v0[q]);
      ph0[4 + q] = f2bh(v1[q]);
      ph1[q]     = f2bh(v2[q]);
      ph1[4 + q] = f2bh(v3[q]);
    }
    short8 b0 = *(const short8*)(wb + k0);
    short8 b1v = *(const short8*)(wb + k0 + 8);
    *(short8*)&Ah[r][s16]     = ph0;
    *(short8*)&Ah[r][s16 + 8] = ph1;
    *(short8*)&Bh[r][s16]     = b0;
    *(short8*)&Bh[r][s16 + 8] = b1v;
    __syncthreads();

    short8 af[4], bf[4];
#pragma unroll
    for (int i = 0; i < 4; ++i) {
      af[i] = *(const short8*)&Ah[wr * 64 + i * 16 + fr][fg * 8];
      bf[i] = *(const short8*)&Bh[wcc * 64 + i * 16 + fr][fg * 8];
    }
#pragma unroll
    for (int i = 0; i < 4; ++i)
#pragma unroll
      for (int j = 0; j < 4; ++j)
        acc[i][j] = __builtin_amdgcn_mfma_f32_16x16x32_bf16(af[i], bf[j], acc[i][j], 0, 0, 0);
    __syncthreads();
  }

  float eb[4];
#pragma unroll
  for (int j = 0; j < 4; ++j) eb[j] = expert_b[e * HD + n0 + wcc * 64 + j * 16 + fr];
#pragma unroll
  for (int i = 0; i < 4; ++i)
#pragma unroll
    for (int j = 0; j < 4; ++j) {
      int col = n0 + wcc * 64 + j * 16 + fr;
#pragma unroll
      for (int q = 0; q < 4; ++q) {
        int rr = wr * 64 + i * 16 + fg * 4 + q;
        if (rr < rows) out[(size_t)toks[rr] * HD + col] = acc[i][j][q] + eb[j];
      }
    }
}

// ---------------------------------------------------------------------------
extern "C" void kernel_launch(void* const* d_in, const int* in_sizes, int n_in,
                              void* d_out, int out_size, void* d_ws, size_t ws_size,
                              hipStream_t stream) {
  const float* x   = (const float*)d_in[0];
  const float* W1  = (const float*)d_in[1];
  const float* b1  = (const float*)d_in[2];
  const float* W2  = (const float*)d_in[3];
  const float* b2  = (const float*)d_in[4];
  const float* eW  = (const float*)d_in[5];
  const float* eb  = (const float*)d_in[6];
  float* out = (float*)d_out;
  char* ws = (char*)d_ws;

  short* W1hT  = (short*)(ws);                 // 1,048,576 B
  short* W1lT  = (short*)(ws + 1048576);       // 1,048,576 B
  short* WexpT = (short*)(ws + 2097152);       // 16,777,216 B
  float* part  = (float*)(ws + 18874368);      // 4,194,304 B
  int* sel     = (int*)(ws + 23068672);        // 131,072 B
  int* flagged = (int*)(ws + 23199744);        // 131,072 B
  int* list    = (int*)(ws + 23330816);        // 1,048,576 B
  int* cnt     = (int*)(ws + 24379392);        // 32 B
  int* nflag   = (int*)(ws + 24379424);        // 4 B
  int* ntl     = (int*)(ws + 24379428);        // 4 B
  int* desc    = (int*)(ws + 24379456);        // 1056 B
  if (ws_size < 24400000) return;

  hipMemsetAsync(ws + 24379392, 0, 40, stream);

  dim3 b256(256);
  k_transpose_split<<<dim3(16, 32, 1), b256, 0, stream>>>(W1, W1hT, W1lT, 1024, 512);
  k_transpose_split<<<dim3(32, 32, 8), b256, 0, stream>>>(eW, WexpT, nullptr, 1024, 1024);
  k_gemm1<<<dim3(256, 4), b256, 0, stream>>>(x, W1hT, W1lT, b1, W2, part);
  k_combine<<<dim3(128), b256, 0, stream>>>(part, b2, sel, flagged, nflag);
  k_recompute<<<dim3(256), b256, 0, stream>>>(x, W1, b1, W2, b2, flagged, nflag, sel);
  k_compact<<<dim3(128), b256, 0, stream>>>(sel, cnt, list);
  k_build_desc<<<dim3(1), dim3(64), 0, stream>>>(cnt, desc, ntl);
  k_gemm2<<<dim3(264, 8), b256, 0, stream>>>(x, WexpT, eb, cnt, list, desc, ntl, out);
}